// Round 3
// baseline (3600.230 us; speedup 1.0000x reference)
//
#include <hip/hip_runtime.h>

#define BATCH  4096
#define TSTEPS 64
#define FDIM   128
#define HDIM   256
#define ODIM   64
#define MROWS  64
#define NBLK   64    // BATCH / MROWS
#define NTHR   512   // 8 waves

#define WARR_BYTES 589824   // 48*12*64*8 bf16

typedef __attribute__((ext_vector_type(8))) short  short8;
typedef __attribute__((ext_vector_type(4))) float  floatx4;

#define MFMA(a,b,c) __builtin_amdgcn_mfma_f32_16x16x32_bf16((a),(b),(c),0,0,0)

__device__ __forceinline__ unsigned short f2bf(float f){
  unsigned u = __builtin_bit_cast(unsigned, f);
  u += 0x7FFFu + ((u >> 16) & 1u);           // RTNE
  return (unsigned short)(u >> 16);
}
__device__ __forceinline__ float sigm(float x){
  return __builtin_amdgcn_rcpf(1.f + __expf(-x));
}
__device__ __forceinline__ float tanh_f(float x){
  return 2.f * __builtin_amdgcn_rcpf(1.f + __expf(-2.f * x)) - 1.f;
}

// ---------------- phase 0: fragment weights + bias tables into d_ws ----------
// warr[((gf*12 + kf)*64 + lane)*8 + i]; gf 0..47, kf 0..7 = w_hh, 8..11 = w_ih
// element = W[16*gf + (lane&15)][32*kf + 8*(lane>>4) + i]  (A-frag, row=lane&15)
// bias tables (float): brz[512] = b_ih+b_hh (r,z cols); bxn[256]=b_ih[n]; bhn[256]=b_hh[n]
__global__ void prep_weights(const float* __restrict__ w_ih,
                             const float* __restrict__ w_hh,
                             const float* __restrict__ b_ih,
                             const float* __restrict__ b_hh,
                             unsigned short* __restrict__ warr,
                             float* __restrict__ brz,
                             float* __restrict__ bxn,
                             float* __restrict__ bhn){
  int idx = blockIdx.x * 256 + threadIdx.x;
  if (idx < 48*12*64){
    int gf   = idx / 768;
    int rr   = idx - gf*768;
    int kf   = rr >> 6;
    int lane = rr & 63;
    int lo = lane & 15, hi = lane >> 4;
    const float* src = (kf < 8) ? (w_hh + (size_t)(16*gf + lo)*HDIM + 32*kf     + 8*hi)
                                : (w_ih + (size_t)(16*gf + lo)*FDIM + 32*(kf-8) + 8*hi);
    unsigned short* dst = warr + (size_t)idx * 8;
    #pragma unroll
    for (int i = 0; i < 8; ++i) dst[i] = f2bf(src[i]);
  } else {
    int k = idx - 48*12*64;
    if (k < 512)       brz[k]       = b_ih[k] + b_hh[k];
    else if (k < 768)  bxn[k - 512] = b_ih[k];
    else if (k < 1024) bhn[k - 768] = b_hh[k - 256];
  }
}

// swizzled LDS B-frag loads: byte = row*stride + (kb ^ ((row&7)<<4))
__device__ __forceinline__ short8 ldsH(const unsigned char* sm, int row, int kb){
  return *(const short8*)(sm + row*512 + (kb ^ ((row & 7) << 4)));
}
__device__ __forceinline__ short8 ldsX(const unsigned char* sm, int row, int kb){
  return *(const short8*)(sm + row*256 + (kb ^ ((row & 7) << 4)));
}

// ---------------- main fused kernel ----------------
__global__ __attribute__((amdgpu_flat_work_group_size(NTHR, NTHR)))
           __attribute__((amdgpu_waves_per_eu(2, 2)))
void gru_fused(const float* __restrict__ feat,
               const unsigned short* __restrict__ warr,
               const float* __restrict__ brz,
               const float* __restrict__ bxn,
               const float* __restrict__ bhn,
               const float* __restrict__ w_pi, const float* __restrict__ b_pi,
               const float* __restrict__ w_vf, const float* __restrict__ b_vf,
               float* __restrict__ out){
  __shared__ __align__(16) unsigned char sm_h[MROWS*512];      // 32KB bf16 [64][256] swizzled
  __shared__ __align__(16) unsigned char sm_x[2][MROWS*256];   // 2x16KB bf16 [64][128] swizzled

  const int tid  = threadIdx.x;
  const int wv   = tid >> 6;
  const int lane = tid & 63;
  const int lo   = lane & 15, hi = lane >> 4;
  const int row0 = blockIdx.x * MROWS;
  const int g4   = wv >> 1;        // gate-col group: cols [64*g4, 64*g4+64)
  const int bp   = wv & 1;         // batch-row pair: rows [32*bp, 32*bp+32) within block

  const unsigned short* wl = warr + lane*8;

  float hold[2][4][4];             // fp32 h state [bfi][mi][j]
  #pragma unroll
  for (int b = 0; b < 2; ++b)
    #pragma unroll
    for (int m = 0; m < 4; ++m)
      #pragma unroll
      for (int j = 0; j < 4; ++j) hold[b][m][j] = 0.f;

  // zero sm_h; stage x[0] into sm_x[0]
  #pragma unroll
  for (int i = 0; i < 4; ++i) ((int4*)sm_h)[tid + i*NTHR] = make_int4(0,0,0,0);
  #pragma unroll
  for (int i = 0; i < 4; ++i){
    int cid = tid + i*NTHR;        // 0..2047
    int r   = cid >> 5;            // 0..63
    int c4  = cid & 31;
    float4 v = *((const float4*)(feat + (size_t)(row0 + r)*(TSTEPS*FDIM)) + c4);
    uint2 pk;
    pk.x = (unsigned)f2bf(v.x) | ((unsigned)f2bf(v.y) << 16);
    pk.y = (unsigned)f2bf(v.z) | ((unsigned)f2bf(v.w) << 16);
    int byte = r*256 + ((c4*8) ^ ((r & 7) << 4));
    *(uint2*)(sm_x[0] + byte) = pk;
  }
  __syncthreads();

  for (int t = 0; t < TSTEPS; ++t){
    const int cur = t & 1, nxt = cur ^ 1;
    const bool pf = (t + 1 < TSTEPS);

    // ---- prefetch x[t+1] (global loads issued early; latency hides under MFMAs)
    float4 xf[4];
    if (pf){
      #pragma unroll
      for (int i = 0; i < 4; ++i){
        int cid = tid + i*NTHR;
        int r   = cid >> 5;
        int c4  = cid & 31;
        xf[i] = *((const float4*)(feat + (size_t)(row0 + r)*(TSTEPS*FDIM) + (size_t)(t+1)*FDIM) + c4);
      }
    }

    // ---- acc init from bias tables (L1-hot float4 loads, D-layout-native)
    floatx4 ar[4][2], az[4][2], anh[4][2], anx[4][2];
    #pragma unroll
    for (int mi = 0; mi < 4; ++mi){
      int cb = 64*g4 + 16*mi + 4*hi;
      floatx4 vr = *(const floatx4*)(brz + cb);
      floatx4 vz = *(const floatx4*)(brz + 256 + cb);
      floatx4 vh = *(const floatx4*)(bhn + cb);
      floatx4 vx = *(const floatx4*)(bxn + cb);
      ar[mi][0]  = vr; ar[mi][1]  = vr;
      az[mi][0]  = vz; az[mi][1]  = vz;
      anh[mi][0] = vh; anh[mi][1] = vh;
      anx[mi][0] = vx; anx[mi][1] = vx;
    }

    // ---- h-part: K=256, A-frags streamed from L2
    #pragma unroll
    for (int kf = 0; kf < 8; ++kf){
      short8 b0 = ldsH(sm_h, 32*bp + lo,      kf*64 + hi*16);
      short8 b1 = ldsH(sm_h, 32*bp + 16 + lo, kf*64 + hi*16);
      #pragma unroll
      for (int i = 0; i < 4; ++i){
        short8 a0 = *(const short8*)(wl + ((     4*g4 + i)*12 + kf)*512);
        short8 a1 = *(const short8*)(wl + ((16 + 4*g4 + i)*12 + kf)*512);
        short8 a2 = *(const short8*)(wl + ((32 + 4*g4 + i)*12 + kf)*512);
        ar[i][0]  = MFMA(a0, b0, ar[i][0]);  ar[i][1]  = MFMA(a0, b1, ar[i][1]);
        az[i][0]  = MFMA(a1, b0, az[i][0]);  az[i][1]  = MFMA(a1, b1, az[i][1]);
        anh[i][0] = MFMA(a2, b0, anh[i][0]); anh[i][1] = MFMA(a2, b1, anh[i][1]);
      }
    }
    // ---- x-part: K=128
    #pragma unroll
    for (int kx = 0; kx < 4; ++kx){
      short8 b0 = ldsX(sm_x[cur], 32*bp + lo,      kx*64 + hi*16);
      short8 b1 = ldsX(sm_x[cur], 32*bp + 16 + lo, kx*64 + hi*16);
      #pragma unroll
      for (int i = 0; i < 4; ++i){
        short8 a0 = *(const short8*)(wl + ((     4*g4 + i)*12 + 8 + kx)*512);
        short8 a1 = *(const short8*)(wl + ((16 + 4*g4 + i)*12 + 8 + kx)*512);
        short8 a2 = *(const short8*)(wl + ((32 + 4*g4 + i)*12 + 8 + kx)*512);
        ar[i][0]  = MFMA(a0, b0, ar[i][0]);  ar[i][1]  = MFMA(a0, b1, ar[i][1]);
        az[i][0]  = MFMA(a1, b0, az[i][0]);  az[i][1]  = MFMA(a1, b1, az[i][1]);
        anx[i][0] = MFMA(a2, b0, anx[i][0]); anx[i][1] = MFMA(a2, b1, anx[i][1]);
      }
    }
    __syncthreads();   // all LDS reads of this step done

    // ---- lane-local gate math; write h_new (bf16, swizzled, 8B packed)
    #pragma unroll
    for (int bfi = 0; bfi < 2; ++bfi){
      int row = 32*bp + 16*bfi + lo;
      #pragma unroll
      for (int mi = 0; mi < 4; ++mi){
        unsigned q[4];
        #pragma unroll
        for (int j = 0; j < 4; ++j){
          float r  = sigm(ar[mi][bfi][j]);
          float z  = sigm(az[mi][bfi][j]);
          float n  = tanh_f(anx[mi][bfi][j] + r*anh[mi][bfi][j]);
          float hv = (1.f - z)*n + z*hold[bfi][mi][j];
          hold[bfi][mi][j] = hv;
          q[j] = f2bf(hv);
        }
        uint2 pk; pk.x = q[0] | (q[1] << 16); pk.y = q[2] | (q[3] << 16);
        int cb   = (64*g4 + 16*mi + 4*hi) * 2;
        int byte = row*512 + (cb ^ ((row & 7) << 4));
        *(uint2*)(sm_h + byte) = pk;
      }
    }
    // ---- write prefetched x[t+1] into the other buffer
    if (pf){
      #pragma unroll
      for (int i = 0; i < 4; ++i){
        int cid = tid + i*NTHR;
        int r   = cid >> 5;
        int c4  = cid & 31;
        uint2 pk;
        pk.x = (unsigned)f2bf(xf[i].x) | ((unsigned)f2bf(xf[i].y) << 16);
        pk.y = (unsigned)f2bf(xf[i].z) | ((unsigned)f2bf(xf[i].w) << 16);
        int byte = r*256 + ((c4*8) ^ ((r & 7) << 4));
        *(uint2*)(sm_x[nxt] + byte) = pk;
      }
    }
    __syncthreads();   // h[t+1], x[t+1] visible
  }

  // ---- epilogue: leaky(h_last) -> sm_h (bf16), then heads
  #pragma unroll
  for (int bfi = 0; bfi < 2; ++bfi){
    int row = 32*bp + 16*bfi + lo;
    #pragma unroll
    for (int mi = 0; mi < 4; ++mi){
      unsigned q[4];
      #pragma unroll
      for (int j = 0; j < 4; ++j){
        float v = hold[bfi][mi][j];
        v = (v >= 0.f) ? v : 0.01f*v;
        q[j] = f2bf(v);
      }
      uint2 pk; pk.x = q[0] | (q[1] << 16); pk.y = q[2] | (q[3] << 16);
      int cb   = (64*g4 + 16*mi + 4*hi) * 2;
      int byte = row*512 + (cb ^ ((row & 7) << 4));
      *(uint2*)(sm_h + byte) = pk;
    }
  }
  __syncthreads();

  const int head = wv >> 2;            // 0 = pi, 1 = vf
  const int mfo  = wv & 3;             // out-dim frag
  const float* wh = head ? w_vf : w_pi;
  const float* bh = head ? b_vf : b_pi;
  floatx4 acc4[4];
  #pragma unroll
  for (int b = 0; b < 4; ++b) acc4[b] = (floatx4){0.f,0.f,0.f,0.f};
  #pragma unroll
  for (int kf = 0; kf < 8; ++kf){
    const float* ap = wh + (size_t)(16*mfo + lo)*HDIM + 32*kf + 8*hi;
    float4 av0 = *(const float4*)ap;
    float4 av1 = *(const float4*)(ap + 4);
    short8 a;
    a[0]=(short)f2bf(av0.x); a[1]=(short)f2bf(av0.y); a[2]=(short)f2bf(av0.z); a[3]=(short)f2bf(av0.w);
    a[4]=(short)f2bf(av1.x); a[5]=(short)f2bf(av1.y); a[6]=(short)f2bf(av1.z); a[7]=(short)f2bf(av1.w);
    #pragma unroll
    for (int b = 0; b < 4; ++b){
      short8 bb = ldsH(sm_h, 16*b + lo, kf*64 + hi*16);
      acc4[b] = MFMA(a, bb, acc4[b]);
    }
  }
  const size_t outoff = (size_t)head * ((size_t)BATCH * ODIM);
  #pragma unroll
  for (int b = 0; b < 4; ++b){
    int grow = row0 + 16*b + lo;
    #pragma unroll
    for (int j = 0; j < 4; ++j){
      int od = 16*mfo + 4*hi + j;
      float v = acc4[b][j] + bh[od];
      v = (v >= 0.f) ? v : 0.01f*v;
      out[outoff + (size_t)grow*ODIM + od] = v;
    }
  }
}

extern "C" void kernel_launch(void* const* d_in, const int* in_sizes, int n_in,
                              void* d_out, int out_size, void* d_ws, size_t ws_size,
                              hipStream_t stream){
  const float* feat = (const float*)d_in[0];
  const float* w_ih = (const float*)d_in[1];
  const float* w_hh = (const float*)d_in[2];
  const float* b_ih = (const float*)d_in[3];
  const float* b_hh = (const float*)d_in[4];
  const float* w_pi = (const float*)d_in[5];
  const float* b_pi = (const float*)d_in[6];
  const float* w_vf = (const float*)d_in[7];
  const float* b_vf = (const float*)d_in[8];

  unsigned short* warr = (unsigned short*)d_ws;
  float* brz = (float*)((char*)d_ws + WARR_BYTES);        // 512 floats
  float* bxn = brz + 512;                                 // 256 floats
  float* bhn = bxn + 256;                                 // 256 floats

  prep_weights<<<148, 256, 0, stream>>>(w_ih, w_hh, b_ih, b_hh, warr, brz, bxn, bhn);
  gru_fused<<<NBLK, NTHR, 0, stream>>>(feat, warr, brz, bxn, bhn,
                                       w_pi, b_pi, w_vf, b_vf, (float*)d_out);
}

// Round 4
// 1336.016 us; speedup vs baseline: 2.6947x; 2.6947x over previous
//
#include <hip/hip_runtime.h>

#define BATCH  4096
#define TSTEPS 64
#define FDIM   128
#define HDIM   256
#define ODIM   64
#define MROWS  64
#define NBLK   64     // BATCH / MROWS
#define NTHR   1024   // 16 waves -> hard cap 128 VGPR/wave, 4 waves/SIMD

#define WARR_BYTES 589824   // 48*12*64*8 bf16
#define SMEM_BYTES 147456   // 32K sm_h + 16K sm_x + 96K wlds

typedef __attribute__((ext_vector_type(8))) short  short8;
typedef __attribute__((ext_vector_type(4))) float  floatx4;

#define MFMA(a,b,c) __builtin_amdgcn_mfma_f32_16x16x32_bf16((a),(b),(c),0,0,0)

__device__ __forceinline__ unsigned short f2bf(float f){
  unsigned u = __builtin_bit_cast(unsigned, f);
  u += 0x7FFFu + ((u >> 16) & 1u);           // RTNE
  return (unsigned short)(u >> 16);
}
__device__ __forceinline__ float sigm(float x){
  return __builtin_amdgcn_rcpf(1.f + __expf(-x));
}
__device__ __forceinline__ float tanh_f(float x){
  return 2.f * __builtin_amdgcn_rcpf(1.f + __expf(-2.f * x)) - 1.f;
}

// ---------------- phase 0: fragment weights + bias tables into d_ws ----------
// warr[((gf*12 + kf)*64 + lane)*8 + i]; gf 0..47, kf 0..7 = w_hh, 8..11 = w_ih
// element = W[16*gf + (lane&15)][32*kf + 8*(lane>>4) + i]  (A-frag, row=lane&15)
__global__ void prep_weights(const float* __restrict__ w_ih,
                             const float* __restrict__ w_hh,
                             const float* __restrict__ b_ih,
                             const float* __restrict__ b_hh,
                             unsigned short* __restrict__ warr,
                             float* __restrict__ brz,
                             float* __restrict__ bxn,
                             float* __restrict__ bhn){
  int idx = blockIdx.x * 256 + threadIdx.x;
  if (idx < 48*12*64){
    int gf   = idx / 768;
    int rr   = idx - gf*768;
    int kf   = rr >> 6;
    int lane = rr & 63;
    int lo = lane & 15, hi = lane >> 4;
    const float* src = (kf < 8) ? (w_hh + (size_t)(16*gf + lo)*HDIM + 32*kf     + 8*hi)
                                : (w_ih + (size_t)(16*gf + lo)*FDIM + 32*(kf-8) + 8*hi);
    unsigned short* dst = warr + (size_t)idx * 8;
    #pragma unroll
    for (int i = 0; i < 8; ++i) dst[i] = f2bf(src[i]);
  } else {
    int k = idx - 48*12*64;
    if (k < 512)       brz[k]       = b_ih[k] + b_hh[k];
    else if (k < 768)  bxn[k - 512] = b_ih[k];
    else if (k < 1024) bhn[k - 768] = b_hh[k - 256];
  }
}

// swizzled LDS B-frag loads: byte = row*stride + (kb ^ ((row&7)<<4))
__device__ __forceinline__ short8 ldsH(const unsigned char* sm, int row, int kb){
  return *(const short8*)(sm + row*512 + (kb ^ ((row & 7) << 4)));
}
__device__ __forceinline__ short8 ldsX(const unsigned char* sm, int row, int kb){
  return *(const short8*)(sm + row*256 + (kb ^ ((row & 7) << 4)));
}

// ---------------- main fused kernel ----------------
__global__ __attribute__((amdgpu_flat_work_group_size(NTHR, NTHR)))
void gru_fused(const float* __restrict__ feat,
               const unsigned short* __restrict__ warr,
               const float* __restrict__ brz,
               const float* __restrict__ bxn,
               const float* __restrict__ bhn,
               const float* __restrict__ w_pi, const float* __restrict__ b_pi,
               const float* __restrict__ w_vf, const float* __restrict__ b_vf,
               float* __restrict__ out){
  extern __shared__ __align__(16) unsigned char smem[];
  unsigned char* sm_h = smem;             // 32 KB bf16 [64][256] swizzled
  unsigned char* sm_x = smem + 32768;     // 16 KB bf16 [64][128] swizzled
  unsigned char* wlds = smem + 49152;     // 96 KB: frag(gf, kf<2) at ((gf*2+kf)*64+lane)*16

  const int tid  = threadIdx.x;
  const int wv   = tid >> 6;              // 0..15
  const int lane = tid & 63;
  const int lo   = lane & 15, hi = lane >> 4;
  const int row0 = blockIdx.x * MROWS;
  const int gfr  = wv, gfz = 16 + wv, gfn = 32 + wv;   // this wave's gate-col frags
  const int cb   = 16*wv + 4*hi;                        // gate/h col base for this lane

  const unsigned short* wl = warr + lane*8;

  // ---- preload wlds (kf 0,1 of all 48 gf): 6144 int4 units
  #pragma unroll
  for (int i = 0; i < 6; ++i){
    int u   = tid + i*NTHR;          // (gf*2 + kf)*64 + lane
    int gfk = u >> 6;
    int ln  = u & 63;
    int gf  = gfk >> 1, kf = gfk & 1;
    ((int4*)wlds)[u] = ((const int4*)warr)[(gf*12 + kf)*64 + ln];
  }
  // ---- zero sm_h (2048 int4)
  #pragma unroll
  for (int i = 0; i < 2; ++i) ((int4*)sm_h)[tid + i*NTHR] = make_int4(0,0,0,0);
  // ---- stage x[0]
  #pragma unroll
  for (int i = 0; i < 2; ++i){
    int cid = tid + i*NTHR;          // 0..2047
    int r   = cid >> 5;              // 0..63
    int c4  = cid & 31;
    floatx4 v = __builtin_nontemporal_load(
        (const floatx4*)(feat + (size_t)(row0 + r)*(TSTEPS*FDIM)) + c4);
    uint2 pk;
    pk.x = (unsigned)f2bf(v[0]) | ((unsigned)f2bf(v[1]) << 16);
    pk.y = (unsigned)f2bf(v[2]) | ((unsigned)f2bf(v[3]) << 16);
    *(uint2*)(sm_x + r*256 + ((c4*8) ^ ((r & 7) << 4))) = pk;
  }

  float hold[4][4];
  #pragma unroll
  for (int m = 0; m < 4; ++m)
    #pragma unroll
    for (int j = 0; j < 4; ++j) hold[m][j] = 0.f;

  __syncthreads();

  for (int t = 0; t < TSTEPS; ++t){
    // ---- acc init from bias tables (gate-col fixed per wave; same for all row-frags)
    floatx4 vr = *(const floatx4*)(brz + cb);
    floatx4 vz = *(const floatx4*)(brz + 256 + cb);
    floatx4 vh = *(const floatx4*)(bhn + cb);
    floatx4 vx = *(const floatx4*)(bxn + cb);
    floatx4 ar[4], az[4], anh[4], anx[4];
    #pragma unroll
    for (int m = 0; m < 4; ++m){ ar[m] = vr; az[m] = vz; anh[m] = vh; anx[m] = vx; }

    // ---- kf 0,1: A from LDS (wlds)
    #pragma unroll
    for (int kf = 0; kf < 2; ++kf){
      short8 a0 = *(const short8*)(wlds + ((gfr*2 + kf)*64 + lane)*16);
      short8 a1 = *(const short8*)(wlds + ((gfz*2 + kf)*64 + lane)*16);
      short8 a2 = *(const short8*)(wlds + ((gfn*2 + kf)*64 + lane)*16);
      #pragma unroll
      for (int m = 0; m < 4; ++m){
        short8 b = ldsH(sm_h, 16*m + lo, kf*64 + hi*16);
        ar[m]  = MFMA(a0, b, ar[m]);
        az[m]  = MFMA(a1, b, az[m]);
        anh[m] = MFMA(a2, b, anh[m]);
      }
    }
    // ---- kf 2..7: A streamed from global (h-part)
    #pragma unroll
    for (int kf = 2; kf < 8; ++kf){
      short8 a0 = *(const short8*)(wl + (gfr*12 + kf)*512);
      short8 a1 = *(const short8*)(wl + (gfz*12 + kf)*512);
      short8 a2 = *(const short8*)(wl + (gfn*12 + kf)*512);
      #pragma unroll
      for (int m = 0; m < 4; ++m){
        short8 b = ldsH(sm_h, 16*m + lo, kf*64 + hi*16);
        ar[m]  = MFMA(a0, b, ar[m]);
        az[m]  = MFMA(a1, b, az[m]);
        anh[m] = MFMA(a2, b, anh[m]);
      }
    }
    // ---- kf 8..11: A streamed from global (x-part)
    #pragma unroll
    for (int kx = 0; kx < 4; ++kx){
      short8 a0 = *(const short8*)(wl + (gfr*12 + 8 + kx)*512);
      short8 a1 = *(const short8*)(wl + (gfz*12 + 8 + kx)*512);
      short8 a2 = *(const short8*)(wl + (gfn*12 + 8 + kx)*512);
      #pragma unroll
      for (int m = 0; m < 4; ++m){
        short8 b = ldsX(sm_x, 16*m + lo, kx*64 + hi*16);
        ar[m]  = MFMA(a0, b, ar[m]);
        az[m]  = MFMA(a1, b, az[m]);
        anx[m] = MFMA(a2, b, anx[m]);
      }
    }
    __syncthreads();   // all sm_h / sm_x reads of this step done

    // ---- lane-local gate math; write h_new (bf16, swizzled, 8B packed)
    #pragma unroll
    for (int m = 0; m < 4; ++m){
      int row = 16*m + lo;
      unsigned q[4];
      #pragma unroll
      for (int j = 0; j < 4; ++j){
        float r  = sigm(ar[m][j]);
        float z  = sigm(az[m][j]);
        float n  = tanh_f(anx[m][j] + r*anh[m][j]);
        float hv = (1.f - z)*n + z*hold[m][j];
        hold[m][j] = hv;
        q[j] = f2bf(hv);
      }
      uint2 pk; pk.x = q[0] | (q[1] << 16); pk.y = q[2] | (q[3] << 16);
      *(uint2*)(sm_h + row*512 + ((cb*2) ^ ((row & 7) << 4))) = pk;
    }
    // ---- stage x[t+1] (nontemporal; sm_x reads for step t finished above)
    if (t + 1 < TSTEPS){
      #pragma unroll
      for (int i = 0; i < 2; ++i){
        int cid = tid + i*NTHR;
        int r   = cid >> 5;
        int c4  = cid & 31;
        floatx4 v = __builtin_nontemporal_load(
            (const floatx4*)(feat + (size_t)(row0 + r)*(TSTEPS*FDIM) + (size_t)(t+1)*FDIM) + c4);
        uint2 pk;
        pk.x = (unsigned)f2bf(v[0]) | ((unsigned)f2bf(v[1]) << 16);
        pk.y = (unsigned)f2bf(v[2]) | ((unsigned)f2bf(v[3]) << 16);
        *(uint2*)(sm_x + r*256 + ((c4*8) ^ ((r & 7) << 4))) = pk;
      }
    }
    __syncthreads();   // h[t+1], x[t+1] visible
  }

  // ---- epilogue: leaky(h_last) -> sm_h (bf16)
  #pragma unroll
  for (int m = 0; m < 4; ++m){
    int row = 16*m + lo;
    unsigned q[4];
    #pragma unroll
    for (int j = 0; j < 4; ++j){
      float v = hold[m][j];
      v = (v >= 0.f) ? v : 0.01f*v;
      q[j] = f2bf(v);
    }
    uint2 pk; pk.x = q[0] | (q[1] << 16); pk.y = q[2] | (q[3] << 16);
    *(uint2*)(sm_h + row*512 + ((cb*2) ^ ((row & 7) << 4))) = pk;
  }
  __syncthreads();

  // ---- heads: 16 waves = 2 heads x 4 out-frags x 2 row-halves
  const int head = wv >> 3;            // 0 = pi, 1 = vf
  const int sub  = wv & 7;
  const int mfo  = sub >> 1;           // out-col frag 0..3
  const int rh   = sub & 1;            // row half: frags {2rh, 2rh+1}
  const float* wh = head ? w_vf : w_pi;
  const float* bh = head ? b_vf : b_pi;
  floatx4 acc0 = {0.f,0.f,0.f,0.f}, acc1 = {0.f,0.f,0.f,0.f};
  #pragma unroll
  for (int kf = 0; kf < 8; ++kf){
    const float* ap = wh + (size_t)(16*mfo + lo)*HDIM + 32*kf + 8*hi;
    float4 av0 = *(const float4*)ap;
    float4 av1 = *(const float4*)(ap + 4);
    short8 a;
    a[0]=(short)f2bf(av0.x); a[1]=(short)f2bf(av0.y); a[2]=(short)f2bf(av0.z); a[3]=(short)f2bf(av0.w);
    a[4]=(short)f2bf(av1.x); a[5]=(short)f2bf(av1.y); a[6]=(short)f2bf(av1.z); a[7]=(short)f2bf(av1.w);
    short8 b0 = ldsH(sm_h, 16*(2*rh)     + lo, kf*64 + hi*16);
    short8 b1 = ldsH(sm_h, 16*(2*rh + 1) + lo, kf*64 + hi*16);
    acc0 = MFMA(a, b0, acc0);
    acc1 = MFMA(a, b1, acc1);
  }
  const size_t outoff = (size_t)head * ((size_t)BATCH * ODIM);
  #pragma unroll
  for (int b = 0; b < 2; ++b){
    floatx4 ac = b ? acc1 : acc0;
    int grow = row0 + 16*(2*rh + b) + lo;
    #pragma unroll
    for (int j = 0; j < 4; ++j){
      int od = 16*mfo + 4*hi + j;
      float v = ac[j] + bh[od];
      v = (v >= 0.f) ? v : 0.01f*v;
      out[outoff + (size_t)grow*ODIM + od] = v;
    }
  }
}

extern "C" void kernel_launch(void* const* d_in, const int* in_sizes, int n_in,
                              void* d_out, int out_size, void* d_ws, size_t ws_size,
                              hipStream_t stream){
  const float* feat = (const float*)d_in[0];
  const float* w_ih = (const float*)d_in[1];
  const float* w_hh = (const float*)d_in[2];
  const float* b_ih = (const float*)d_in[3];
  const float* b_hh = (const float*)d_in[4];
  const float* w_pi = (const float*)d_in[5];
  const float* b_pi = (const float*)d_in[6];
  const float* w_vf = (const float*)d_in[7];
  const float* b_vf = (const float*)d_in[8];

  unsigned short* warr = (unsigned short*)d_ws;
  float* brz = (float*)((char*)d_ws + WARR_BYTES);        // 512 floats
  float* bxn = brz + 512;                                 // 256 floats
  float* bhn = bxn + 256;                                 // 256 floats

  hipFuncSetAttribute((const void*)gru_fused,
                      hipFuncAttributeMaxDynamicSharedMemorySize, SMEM_BYTES);

  prep_weights<<<148, 256, 0, stream>>>(w_ih, w_hh, b_ih, b_hh, warr, brz, bxn, bhn);
  gru_fused<<<NBLK, NTHR, SMEM_BYTES, stream>>>(feat, warr, brz, bxn, bhn,
                                                w_pi, b_pi, w_vf, b_vf, (float*)d_out);
}

// Round 6
// 1292.218 us; speedup vs baseline: 2.7861x; 1.0339x over previous
//
#include <hip/hip_runtime.h>

#define BATCH  4096
#define TSTEPS 64
#define FDIM   128
#define HDIM   256
#define ODIM   64
#define MROWS  64
#define NBLK   64     // BATCH / MROWS
#define NTHR   1024   // 16 waves; combined VGPR+AGPR cap = 128/wave (self-enforcing)

#define WARR_BYTES 589824   // 48*12*64*8 bf16
// dynamic smem layout
#define SMH_OFF   0         // 32 KB  bf16 [64][256] swizzled
#define SMX_OFF   32768     // 16 KB  bf16 [64][128] swizzled
#define BIAS_OFF  49152     // 4 KB   float[1024]
#define RING_OFF  53248     // 96 KB  16 waves x 2 slots x 3 frags x 1024 B
#define SMEM_BYTES 151552

typedef __attribute__((ext_vector_type(8))) short  short8;
typedef __attribute__((ext_vector_type(4))) float  floatx4;

#define MFMA(a,b,c) __builtin_amdgcn_mfma_f32_16x16x32_bf16((a),(b),(c),0,0,0)

__device__ __forceinline__ unsigned short f2bf(float f){
  unsigned u = __builtin_bit_cast(unsigned, f);
  u += 0x7FFFu + ((u >> 16) & 1u);           // RTNE
  return (unsigned short)(u >> 16);
}
__device__ __forceinline__ float sigm(float x){
  return __builtin_amdgcn_rcpf(1.f + __expf(-x));
}
__device__ __forceinline__ float tanh_f(float x){
  return 2.f * __builtin_amdgcn_rcpf(1.f + __expf(-2.f * x)) - 1.f;
}

// async 16B/lane global -> LDS (dest = wave-uniform base + lane*16, HW-implicit)
__device__ __forceinline__ void dma16(const void* g, void* l){
  __builtin_amdgcn_global_load_lds(
      (const __attribute__((address_space(1))) unsigned int*)g,
      (__attribute__((address_space(3))) unsigned int*)l, 16, 0, 0);
}

// ---------------- phase 0: fragment weights into d_ws ----------
// warr[((gf*12 + kf)*64 + lane)*8 + i]; gf 0..47, kf 0..7 = w_hh, 8..11 = w_ih
// element = W[16*gf + (lane&15)][32*kf + 8*(lane>>4) + i]  (A-frag, row=lane&15)
__global__ void prep_weights(const float* __restrict__ w_ih,
                             const float* __restrict__ w_hh,
                             unsigned short* __restrict__ warr){
  int idx = blockIdx.x * 256 + threadIdx.x;
  if (idx >= 48*12*64) return;
  int gf   = idx / 768;
  int rr   = idx - gf*768;
  int kf   = rr >> 6;
  int lane = rr & 63;
  int lo = lane & 15, hi = lane >> 4;
  const float* src = (kf < 8) ? (w_hh + (size_t)(16*gf + lo)*HDIM + 32*kf     + 8*hi)
                              : (w_ih + (size_t)(16*gf + lo)*FDIM + 32*(kf-8) + 8*hi);
  unsigned short* dst = warr + (size_t)idx * 8;
  #pragma unroll
  for (int i = 0; i < 8; ++i) dst[i] = f2bf(src[i]);
}

// swizzled LDS B-frag loads: byte = row*stride + (kb ^ ((row&7)<<4))
__device__ __forceinline__ short8 ldsH(const unsigned char* sm, int row, int kb){
  return *(const short8*)(sm + row*512 + (kb ^ ((row & 7) << 4)));
}
__device__ __forceinline__ short8 ldsX(const unsigned char* sm, int row, int kb){
  return *(const short8*)(sm + row*256 + (kb ^ ((row & 7) << 4)));
}

#define ROUND(G) { \
    constexpr int KF = ((G) + KOFF) % 12; \
    asm volatile("s_waitcnt vmcnt(%0)" :: "i"((G) >= 10 ? 5 : 3) : "memory"); \
    const unsigned char* rs = ring_r + ((G) & 1) * 3072; \
    short8 a0 = *(const short8*)(rs); \
    short8 a1 = *(const short8*)(rs + 1024); \
    short8 a2 = *(const short8*)(rs + 2048); \
    _Pragma("unroll") \
    for (int m = 0; m < 4; ++m){ \
      short8 b = (KF < 8) ? ldsH(sm_h, 16*m + lo, KF*64 + hi*16) \
                          : ldsX(sm_x, 16*m + lo, (KF-8)*64 + hi*16); \
      ar[m] = MFMA(a0, b, ar[m]); \
      az[m] = MFMA(a1, b, az[m]); \
      if (KF < 8) anh[m] = MFMA(a2, b, anh[m]); \
      else        anx[m] = MFMA(a2, b, anx[m]); \
    } \
    asm volatile("s_waitcnt lgkmcnt(0)" ::: "memory"); \
    { constexpr int KF2 = ((G) + 2 + KOFF) % 12; \
      unsigned char* dst = ring_w + ((G) & 1) * 3072; \
      dma16(wsrc + (size_t)KF2*1024,         dst); \
      dma16(wsrc + (size_t)(192+KF2)*1024,   dst + 1024); \
      dma16(wsrc + (size_t)(384+KF2)*1024,   dst + 2048); } \
    if ((G) == 9){ \
      int tn = (t < TSTEPS-1) ? (t+1) : (TSTEPS-1); \
      int r0i = tid >> 5, c0 = tid & 31; \
      int r1i = (tid + NTHR) >> 5; \
      xf0 = __builtin_nontemporal_load( \
        (const floatx4*)(feat + (size_t)(row0 + r0i)*(TSTEPS*FDIM) + (size_t)tn*FDIM) + c0); \
      xf1 = __builtin_nontemporal_load( \
        (const floatx4*)(feat + (size_t)(row0 + r1i)*(TSTEPS*FDIM) + (size_t)tn*FDIM) + c0); \
    } \
  }

template<int KOFF>
__device__ __forceinline__ void gru_body(
    const float* __restrict__ feat, const unsigned short* __restrict__ warr,
    const float* __restrict__ b_ih, const float* __restrict__ b_hh,
    const float* __restrict__ w_pi, const float* __restrict__ b_pi,
    const float* __restrict__ w_vf, const float* __restrict__ b_vf,
    float* __restrict__ out, unsigned char* smem){

  unsigned char* sm_h  = smem + SMH_OFF;
  unsigned char* sm_x  = smem + SMX_OFF;
  float*         biasL = (float*)(smem + BIAS_OFF);

  const int tid  = threadIdx.x;
  const int wv   = tid >> 6;              // 0..15
  const int lane = tid & 63;
  const int lo   = lane & 15, hi = lane >> 4;
  const int row0 = blockIdx.x * MROWS;
  const int cb   = 16*wv + 4*hi;          // gate/h col base for this lane

  const unsigned char* wsrc   = (const unsigned char*)warr + (size_t)wv*12*1024 + lane*16;
  const unsigned char* ring_r = smem + RING_OFF + wv*6144 + lane*16;
  unsigned char*       ring_w = smem + RING_OFF + wv*6144;   // uniform; HW adds lane*16

  // ---- one-time: bias -> LDS
  {
    int c = tid;
    if      (c < 512)  biasL[c] = b_ih[c] + b_hh[c];          // r,z combined
    else if (c < 768)  biasL[c] = b_ih[512 + (c - 512)];      // xn
    else               biasL[c] = b_hh[512 + (c - 768)];      // hn
  }
  // ---- zero sm_h
  #pragma unroll
  for (int i = 0; i < 2; ++i) ((int4*)sm_h)[tid + i*NTHR] = make_int4(0,0,0,0);
  // ---- stage x[0] (swizzled bf16)
  #pragma unroll
  for (int i = 0; i < 2; ++i){
    int cid = tid + i*NTHR;
    int r   = cid >> 5;
    int c4  = cid & 31;
    floatx4 v = __builtin_nontemporal_load(
        (const floatx4*)(feat + (size_t)(row0 + r)*(TSTEPS*FDIM)) + c4);
    uint2 pk;
    pk.x = (unsigned)f2bf(v[0]) | ((unsigned)f2bf(v[1]) << 16);
    pk.y = (unsigned)f2bf(v[2]) | ((unsigned)f2bf(v[3]) << 16);
    *(uint2*)(sm_x + r*256 + ((c4*8) ^ ((r & 7) << 4))) = pk;
  }

  float hold[4][4];
  #pragma unroll
  for (int m = 0; m < 4; ++m)
    #pragma unroll
    for (int j = 0; j < 4; ++j) hold[m][j] = 0.f;

  __syncthreads();   // also drains vmcnt -> clean counter slate

  // ---- prologue: DMA rounds 0,1
  {
    constexpr int K0 = (0 + KOFF) % 12;
    constexpr int K1 = (1 + KOFF) % 12;
    dma16(wsrc + (size_t)K0*1024,        ring_w);
    dma16(wsrc + (size_t)(192+K0)*1024,  ring_w + 1024);
    dma16(wsrc + (size_t)(384+K0)*1024,  ring_w + 2048);
    dma16(wsrc + (size_t)K1*1024,        ring_w + 3072);
    dma16(wsrc + (size_t)(192+K1)*1024,  ring_w + 4096);
    dma16(wsrc + (size_t)(384+K1)*1024,  ring_w + 5120);
  }

  #pragma unroll 1
  for (int t = 0; t < TSTEPS; ++t){
    // acc init from LDS bias
    floatx4 vr = *(const floatx4*)(biasL + cb);
    floatx4 vz = *(const floatx4*)(biasL + 256 + cb);
    floatx4 vx = *(const floatx4*)(biasL + 512 + cb);
    floatx4 vh = *(const floatx4*)(biasL + 768 + cb);
    floatx4 ar[4], az[4], anh[4], anx[4];
    #pragma unroll
    for (int m = 0; m < 4; ++m){ ar[m] = vr; az[m] = vz; anh[m] = vh; anx[m] = vx; }

    floatx4 xf0, xf1;
    ROUND(0) ROUND(1) ROUND(2) ROUND(3) ROUND(4)  ROUND(5)
    ROUND(6) ROUND(7) ROUND(8) ROUND(9) ROUND(10) ROUND(11)

    __syncthreads();   // all sm_h/sm_x reads of this step done
    asm volatile("s_waitcnt vmcnt(6)" ::: "memory");   // xf done; next-step DMAs stay in flight

    // write x[t+1]
    if (t < TSTEPS-1){
      int r0i = tid >> 5, c0 = tid & 31;
      uint2 pk;
      pk.x = (unsigned)f2bf(xf0[0]) | ((unsigned)f2bf(xf0[1]) << 16);
      pk.y = (unsigned)f2bf(xf0[2]) | ((unsigned)f2bf(xf0[3]) << 16);
      *(uint2*)(sm_x + r0i*256 + ((c0*8) ^ ((r0i & 7) << 4))) = pk;
      int r1i = (tid + NTHR) >> 5;
      pk.x = (unsigned)f2bf(xf1[0]) | ((unsigned)f2bf(xf1[1]) << 16);
      pk.y = (unsigned)f2bf(xf1[2]) | ((unsigned)f2bf(xf1[3]) << 16);
      *(uint2*)(sm_x + r1i*256 + ((c0*8) ^ ((r1i & 7) << 4))) = pk;
    }

    // lane-local gate math; write h_new (bf16, swizzled, 8B packed)
    #pragma unroll
    for (int m = 0; m < 4; ++m){
      int row = 16*m + lo;
      unsigned q[4];
      #pragma unroll
      for (int j = 0; j < 4; ++j){
        float r  = sigm(ar[m][j]);
        float z  = sigm(az[m][j]);
        float n  = tanh_f(anx[m][j] + r*anh[m][j]);
        float hv = (1.f - z)*n + z*hold[m][j];
        hold[m][j] = hv;
        q[j] = f2bf(hv);
      }
      uint2 pk; pk.x = q[0] | (q[1] << 16); pk.y = q[2] | (q[3] << 16);
      *(uint2*)(sm_h + row*512 + ((cb*2) ^ ((row & 7) << 4))) = pk;
    }
    __syncthreads();   // h[t+1], x[t+1] visible
  }

  // ---- epilogue: leaky(h_last) -> sm_h (bf16)
  #pragma unroll
  for (int m = 0; m < 4; ++m){
    int row = 16*m + lo;
    unsigned q[4];
    #pragma unroll
    for (int j = 0; j < 4; ++j){
      float v = hold[m][j];
      v = (v >= 0.f) ? v : 0.01f*v;
      q[j] = f2bf(v);
    }
    uint2 pk; pk.x = q[0] | (q[1] << 16); pk.y = q[2] | (q[3] << 16);
    *(uint2*)(sm_h + row*512 + ((cb*2) ^ ((row & 7) << 4))) = pk;
  }
  __syncthreads();

  // ---- heads: 16 waves = 2 heads x 4 out-frags x 2 row-halves
  const int head = wv >> 3;
  const int sub  = wv & 7;
  const int mfo  = sub >> 1;
  const int rh   = sub & 1;
  const float* wh = head ? w_vf : w_pi;
  const float* bh = head ? b_vf : b_pi;
  floatx4 acc0 = {0.f,0.f,0.f,0.f}, acc1 = {0.f,0.f,0.f,0.f};
  #pragma unroll
  for (int kf = 0; kf < 8; ++kf){
    const float* ap = wh + (size_t)(16*mfo + lo)*HDIM + 32*kf + 8*hi;
    floatx4 av0 = *(const floatx4*)ap;
    floatx4 av1 = *(const floatx4*)(ap + 4);
    short8 a;
    a[0]=(short)f2bf(av0[0]); a[1]=(short)f2bf(av0[1]); a[2]=(short)f2bf(av0[2]); a[3]=(short)f2bf(av0[3]);
    a[4]=(short)f2bf(av1[0]); a[5]=(short)f2bf(av1[1]); a[6]=(short)f2bf(av1[2]); a[7]=(short)f2bf(av1[3]);
    short8 b0 = ldsH(sm_h, 16*(2*rh)     + lo, kf*64 + hi*16);
    short8 b1 = ldsH(sm_h, 16*(2*rh + 1) + lo, kf*64 + hi*16);
    acc0 = MFMA(a, b0, acc0);
    acc1 = MFMA(a, b1, acc1);
  }
  const size_t outoff = (size_t)head * ((size_t)BATCH * ODIM);
  #pragma unroll
  for (int b = 0; b < 2; ++b){
    floatx4 ac = b ? acc1 : acc0;
    int grow = row0 + 16*(2*rh + b) + lo;
    #pragma unroll
    for (int j = 0; j < 4; ++j){
      int od = 16*mfo + 4*hi + j;
      float v = ac[j] + bh[od];
      v = (v >= 0.f) ? v : 0.01f*v;
      out[outoff + (size_t)grow*ODIM + od] = v;
    }
  }
}

__global__ __attribute__((amdgpu_flat_work_group_size(NTHR, NTHR)))
void gru_fused(const float* __restrict__ feat, const unsigned short* __restrict__ warr,
               const float* __restrict__ b_ih, const float* __restrict__ b_hh,
               const float* __restrict__ w_pi, const float* __restrict__ b_pi,
               const float* __restrict__ w_vf, const float* __restrict__ b_vf,
               float* __restrict__ out){
  extern __shared__ __align__(16) unsigned char smem[];
  if (blockIdx.x & 1)
    gru_body<6>(feat, warr, b_ih, b_hh, w_pi, b_pi, w_vf, b_vf, out, smem);
  else
    gru_body<0>(feat, warr, b_ih, b_hh, w_pi, b_pi, w_vf, b_vf, out, smem);
}

extern "C" void kernel_launch(void* const* d_in, const int* in_sizes, int n_in,
                              void* d_out, int out_size, void* d_ws, size_t ws_size,
                              hipStream_t stream){
  const float* feat = (const float*)d_in[0];
  const float* w_ih = (const float*)d_in[1];
  const float* w_hh = (const float*)d_in[2];
  const float* b_ih = (const float*)d_in[3];
  const float* b_hh = (const float*)d_in[4];
  const float* w_pi = (const float*)d_in[5];
  const float* b_pi = (const float*)d_in[6];
  const float* w_vf = (const float*)d_in[7];
  const float* b_vf = (const float*)d_in[8];

  unsigned short* warr = (unsigned short*)d_ws;

  hipFuncSetAttribute((const void*)gru_fused,
                      hipFuncAttributeMaxDynamicSharedMemorySize, SMEM_BYTES);

  prep_weights<<<144, 256, 0, stream>>>(w_ih, w_hh, warr);
  gru_fused<<<NBLK, NTHR, SMEM_BYTES, stream>>>(feat, warr, b_ih, b_hh,
                                                w_pi, b_pi, w_vf, b_vf, (float*)d_out);
}

// Round 7
// 839.258 us; speedup vs baseline: 4.2898x; 1.5397x over previous
//
#include <hip/hip_runtime.h>

#define BATCH  4096
#define TSTEPS 64
#define FDIM   128
#define HDIM   256
#define ODIM   64
#define MROWS  32
#define NBLK   128    // BATCH / MROWS
#define NTHR   1024   // 16 waves; 4 waves/SIMD -> 128 reg cap enforced by HW fit

typedef __attribute__((ext_vector_type(8))) short  short8;
typedef __attribute__((ext_vector_type(4))) float  floatx4;

#define MFMA(a,b,c) __builtin_amdgcn_mfma_f32_16x16x32_bf16((a),(b),(c),0,0,0)

__device__ __forceinline__ unsigned short f2bf(float f){
  unsigned u = __builtin_bit_cast(unsigned, f);
  u += 0x7FFFu + ((u >> 16) & 1u);           // RTNE
  return (unsigned short)(u >> 16);
}
__device__ __forceinline__ float sigm(float x){
  return __builtin_amdgcn_rcpf(1.f + __expf(-x));
}
__device__ __forceinline__ float tanh_f(float x){
  return 2.f * __builtin_amdgcn_rcpf(1.f + __expf(-2.f * x)) - 1.f;
}

// ---------------- phase 0: fragment weights into d_ws ----------
// warr[((gf*12 + kf)*64 + lane)*8 + i]; gf 0..47, kf 0..7 = w_hh, 8..11 = w_ih
// element = W[16*gf + (lane&15)][32*kf + 8*(lane>>4) + i]  (A-frag, row=lane&15)
__global__ void prep_weights(const float* __restrict__ w_ih,
                             const float* __restrict__ w_hh,
                             unsigned short* __restrict__ warr){
  int idx = blockIdx.x * 256 + threadIdx.x;
  if (idx >= 48*12*64) return;
  int gf   = idx / 768;
  int rr   = idx - gf*768;
  int kf   = rr >> 6;
  int lane = rr & 63;
  int lo = lane & 15, hi = lane >> 4;
  const float* src = (kf < 8) ? (w_hh + (size_t)(16*gf + lo)*HDIM + 32*kf     + 8*hi)
                              : (w_ih + (size_t)(16*gf + lo)*FDIM + 32*(kf-8) + 8*hi);
  unsigned short* dst = warr + (size_t)idx * 8;
  #pragma unroll
  for (int i = 0; i < 8; ++i) dst[i] = f2bf(src[i]);
}

// ---- LDS swizzle: XOR the 64-B slot index with row bits -> rows spread over
// both 16-bank halves; 1 KB wave-read = 8 cycles (conflict-minimal).
__device__ __forceinline__ short8 ldsH(const unsigned char* sm, int row, int cbyte){
  return *(const short8*)(sm + row*512 + (cbyte ^ ((row & 7) << 6)));
}
__device__ __forceinline__ short8 ldsX(const unsigned char* sm, int row, int cbyte){
  return *(const short8*)(sm + row*256 + (cbyte ^ ((row & 3) << 6)));
}

// ---------------- main fused kernel ----------------
__global__ __attribute__((amdgpu_flat_work_group_size(NTHR, NTHR)))
void gru_fused(const float* __restrict__ feat,
               const unsigned short* __restrict__ warr,
               const float* __restrict__ b_ih, const float* __restrict__ b_hh,
               const float* __restrict__ w_pi, const float* __restrict__ b_pi,
               const float* __restrict__ w_vf, const float* __restrict__ b_vf,
               float* __restrict__ out){
  __shared__ __align__(16) unsigned char sm_h[MROWS*512];   // 16 KB bf16 [32][256] swizzled
  __shared__ __align__(16) unsigned char sm_x[MROWS*256];   // 8 KB  bf16 [32][128] swizzled
  __shared__ __align__(16) float biasL[1024];               // 4 KB bias tables

  const int tid  = threadIdx.x;
  const int wv   = tid >> 6;              // 0..15 -> owns h-cols [16wv, 16wv+16)
  const int lane = tid & 63;
  const int lo   = lane & 15, hi = lane >> 4;
  const int row0 = blockIdx.x * MROWS;
  const int cb   = 16*wv + 4*hi;          // gate/h col base for this lane
  const int gfr  = wv, gfz = 16 + wv, gfn = 32 + wv;

  const unsigned short* wl = warr + lane*8;

  // ---- one-time: bias -> LDS (1024 threads, 1 elem each)
  if      (tid < 512) biasL[tid] = b_ih[tid] + b_hh[tid];   // r,z combined
  else if (tid < 768) biasL[tid] = b_ih[tid];               // xn (b_ih[512+k])
  else                biasL[tid] = b_hh[tid - 256];         // hn (b_hh[512+k])

  // ---- zero sm_h (1024 int4 = 16 KB)
  ((int4*)sm_h)[tid] = make_int4(0,0,0,0);
  // ---- stage x[0]: 32 rows x 32 float4 chunks = 1024 -> one per thread
  {
    int r  = tid >> 5;
    int c4 = tid & 31;
    floatx4 v = __builtin_nontemporal_load(
        (const floatx4*)(feat + (size_t)(row0 + r)*(TSTEPS*FDIM)) + c4);
    uint2 pk;
    pk.x = (unsigned)f2bf(v[0]) | ((unsigned)f2bf(v[1]) << 16);
    pk.y = (unsigned)f2bf(v[2]) | ((unsigned)f2bf(v[3]) << 16);
    int cbyte = c4*8;
    *(uint2*)(sm_x + r*256 + (cbyte ^ ((r & 3) << 6))) = pk;
  }

  float hold[2][4];
  #pragma unroll
  for (int m = 0; m < 2; ++m)
    #pragma unroll
    for (int j = 0; j < 4; ++j) hold[m][j] = 0.f;

  __syncthreads();

  const int xr  = tid >> 5;     // x-staging row/chunk for this thread
  const int xc4 = tid & 31;

  #pragma unroll 1
  for (int t = 0; t < TSTEPS; ++t){
    // ---- prefetch x[t+1] (1 float4/thread; written after mid-barrier)
    int tn = (t < TSTEPS-1) ? (t+1) : (TSTEPS-1);
    floatx4 xf = __builtin_nontemporal_load(
        (const floatx4*)(feat + (size_t)(row0 + xr)*(TSTEPS*FDIM) + (size_t)tn*FDIM) + xc4);

    // ---- acc init from LDS bias
    floatx4 ar[2], az[2], anh[2], anx[2];
    {
      floatx4 vr = *(const floatx4*)(biasL + cb);
      floatx4 vz = *(const floatx4*)(biasL + 256 + cb);
      floatx4 vx = *(const floatx4*)(biasL + 512 + cb);
      floatx4 vh = *(const floatx4*)(biasL + 768 + cb);
      #pragma unroll
      for (int m = 0; m < 2; ++m){ ar[m] = vr; az[m] = vz; anh[m] = vh; anx[m] = vx; }
    }

    // ---- h-part: K=256 (kf 0..7); A direct from global (L2-resident)
    #pragma unroll
    for (int kf = 0; kf < 8; ++kf){
      short8 a0 = *(const short8*)(wl + (gfr*12 + kf)*512);
      short8 a1 = *(const short8*)(wl + (gfz*12 + kf)*512);
      short8 a2 = *(const short8*)(wl + (gfn*12 + kf)*512);
      #pragma unroll
      for (int m = 0; m < 2; ++m){
        short8 b = ldsH(sm_h, 16*m + lo, kf*64 + hi*16);
        ar[m]  = MFMA(a0, b, ar[m]);
        az[m]  = MFMA(a1, b, az[m]);
        anh[m] = MFMA(a2, b, anh[m]);
      }
    }
    // ---- x-part: K=128 (kx 0..3)
    #pragma unroll
    for (int kx = 0; kx < 4; ++kx){
      short8 a0 = *(const short8*)(wl + (gfr*12 + 8 + kx)*512);
      short8 a1 = *(const short8*)(wl + (gfz*12 + 8 + kx)*512);
      short8 a2 = *(const short8*)(wl + (gfn*12 + 8 + kx)*512);
      #pragma unroll
      for (int m = 0; m < 2; ++m){
        short8 b = ldsX(sm_x, 16*m + lo, kx*64 + hi*16);
        ar[m]  = MFMA(a0, b, ar[m]);
        az[m]  = MFMA(a1, b, az[m]);
        anx[m] = MFMA(a2, b, anx[m]);
      }
    }
    __syncthreads();   // all sm_h / sm_x reads of this step done

    // ---- write x[t+1]
    if (t < TSTEPS-1){
      uint2 pk;
      pk.x = (unsigned)f2bf(xf[0]) | ((unsigned)f2bf(xf[1]) << 16);
      pk.y = (unsigned)f2bf(xf[2]) | ((unsigned)f2bf(xf[3]) << 16);
      int cbyte = xc4*8;
      *(uint2*)(sm_x + xr*256 + (cbyte ^ ((xr & 3) << 6))) = pk;
    }

    // ---- lane-local gate math; write h_new (bf16, swizzled, 8B packed)
    #pragma unroll
    for (int m = 0; m < 2; ++m){
      int row = 16*m + lo;
      unsigned q[4];
      #pragma unroll
      for (int j = 0; j < 4; ++j){
        float r  = sigm(ar[m][j]);
        float z  = sigm(az[m][j]);
        float n  = tanh_f(anx[m][j] + r*anh[m][j]);
        float hv = (1.f - z)*n + z*hold[m][j];
        hold[m][j] = hv;
        q[j] = f2bf(hv);
      }
      uint2 pk; pk.x = q[0] | (q[1] << 16); pk.y = q[2] | (q[3] << 16);
      int cbyte = cb*2;
      *(uint2*)(sm_h + row*512 + (cbyte ^ ((row & 7) << 6))) = pk;
    }
    __syncthreads();   // h[t+1], x[t+1] visible
  }

  // ---- epilogue: leaky(h_last) -> sm_h (bf16)
  #pragma unroll
  for (int m = 0; m < 2; ++m){
    int row = 16*m + lo;
    unsigned q[4];
    #pragma unroll
    for (int j = 0; j < 4; ++j){
      float v = hold[m][j];
      v = (v >= 0.f) ? v : 0.01f*v;
      q[j] = f2bf(v);
    }
    uint2 pk; pk.x = q[0] | (q[1] << 16); pk.y = q[2] | (q[3] << 16);
    int cbyte = cb*2;
    *(uint2*)(sm_h + row*512 + (cbyte ^ ((row & 7) << 6))) = pk;
  }
  __syncthreads();

  // ---- heads: 16 waves = 2 heads x 4 out-frags x 2 row-frags
  const int head = wv >> 3;            // 0 = pi, 1 = vf
  const int mfo  = (wv >> 1) & 3;      // out-col frag
  const int rh   = wv & 1;             // row frag
  const float* wh = head ? w_vf : w_pi;
  const float* bh = head ? b_vf : b_pi;
  floatx4 acc = {0.f,0.f,0.f,0.f};
  #pragma unroll
  for (int kf = 0; kf < 8; ++kf){
    const float* ap = wh + (size_t)(16*mfo + lo)*HDIM + 32*kf + 8*hi;
    floatx4 av0 = *(const floatx4*)ap;
    floatx4 av1 = *(const floatx4*)(ap + 4);
    short8 a;
    a[0]=(short)f2bf(av0[0]); a[1]=(short)f2bf(av0[1]); a[2]=(short)f2bf(av0[2]); a[3]=(short)f2bf(av0[3]);
    a[4]=(short)f2bf(av1[0]); a[5]=(short)f2bf(av1[1]); a[6]=(short)f2bf(av1[2]); a[7]=(short)f2bf(av1[3]);
    short8 b = ldsH(sm_h, 16*rh + lo, kf*64 + hi*16);
    acc = MFMA(a, b, acc);
  }
  const size_t outoff = (size_t)head * ((size_t)BATCH * ODIM);
  {
    int grow = row0 + 16*rh + lo;
    #pragma unroll
    for (int j = 0; j < 4; ++j){
      int od = 16*mfo + 4*hi + j;
      float v = acc[j] + bh[od];
      v = (v >= 0.f) ? v : 0.01f*v;
      out[outoff + (size_t)grow*ODIM + od] = v;
    }
  }
}

extern "C" void kernel_launch(void* const* d_in, const int* in_sizes, int n_in,
                              void* d_out, int out_size, void* d_ws, size_t ws_size,
                              hipStream_t stream){
  const float* feat = (const float*)d_in[0];
  const float* w_ih = (const float*)d_in[1];
  const float* w_hh = (const float*)d_in[2];
  const float* b_ih = (const float*)d_in[3];
  const float* b_hh = (const float*)d_in[4];
  const float* w_pi = (const float*)d_in[5];
  const float* b_pi = (const float*)d_in[6];
  const float* w_vf = (const float*)d_in[7];
  const float* b_vf = (const float*)d_in[8];

  unsigned short* warr = (unsigned short*)d_ws;   // 589824 B

  prep_weights<<<144, 256, 0, stream>>>(w_ih, w_hh, warr);
  gru_fused<<<NBLK, NTHR, 0, stream>>>(feat, warr, b_ih, b_hh,
                                       w_pi, b_pi, w_vf, b_vf, (float*)d_out);
}